// Round 10
// baseline (18.711 us; speedup 1.0000x reference)
//
#include <hip/hip_runtime.h>

#define NT    512   // threads per pair-kernel block (8 waves)
#define SPLIT 2     // sub-blocks per row-group pair
#define ROWS  8     // rows register-blocked per group
#define NW    (NT / 64)

__device__ __forceinline__ float pair_loss(float tt, float pp, float tj, float pj, float margin) {
    float td = tt - tj;
    float pd = pp - pj;
    float cs = copysignf(1.0f, td);            // ties -> +/-1; off-diagonal ties have ~0 probability
    return fmaxf(fmaf(-cs, pd, margin), 0.0f);
}

__device__ __forceinline__ void do_j(float tj, float pj, const float* tg, const float* pg,
                                     float margin, float* av) {
    #pragma unroll
    for (int k = 0; k < ROWS; ++k) av[k] += pair_loss(tg[k], pg[k], tj, pj, margin);
}

// ---- kernel 1: all pairs; cheap per-block f32 margin prologue; plain partial stores ----
__global__ __launch_bounds__(NT, 8)
void pair_kernel(const float* __restrict__ preds, const float* __restrict__ targets,
                 double* __restrict__ partials, int N)
{
    const int tid = threadIdx.x, lane = tid & 63, wave = tid >> 6;
    __shared__ float  sred[2 * NW];
    __shared__ double redd[NW];

    // ---- lean f32 margin = 0.25 * std(targets, ddof=1), redundant per block ----
    float margin;
    {
        float s = 0.0f, s2 = 0.0f;
        const int n4 = N >> 2;
        const float4* t4 = (const float4*)targets;
        for (int i = tid; i < n4; i += NT) {
            float4 v = t4[i];
            s  += v.x + v.y + v.z + v.w;
            s2 += v.x * v.x + v.y * v.y + v.z * v.z + v.w * v.w;
        }
        for (int i = (n4 << 2) + tid; i < N; i += NT) { float t = targets[i]; s += t; s2 += t * t; }
        #pragma unroll
        for (int off = 32; off; off >>= 1) { s += __shfl_xor(s, off, 64); s2 += __shfl_xor(s2, off, 64); }
        if (lane == 0) { sred[wave] = s; sred[NW + wave] = s2; }
        __syncthreads();
        float S = 0.0f, S2 = 0.0f;
        #pragma unroll
        for (int w = 0; w < NW; ++w) { S += sred[w]; S2 += sred[NW + w]; }
        float mean = S / (float)N;
        float var  = (S2 - (float)N * mean * mean) / (float)(N - 1);
        margin = 0.25f * sqrtf(fmaxf(var, 0.0f));
    }

    const int G = N >> 3;                 // groups of ROWS rows
    const int P = G >> 1;                 // group pairs (g, G-1-g): uniform combined work
    const int NB = (int)gridDim.x;        // multiple of SPLIT
    const int sub = (int)(blockIdx.x & (SPLIT - 1));
    const int pairblk = (int)(blockIdx.x >> 1);       // / SPLIT
    const int PSTRIDE = NB >> 1;                      // / SPLIT

    float av[ROWS];
    #pragma unroll
    for (int k = 0; k < ROWS; ++k) av[k] = 0.0f;
    float extra = 0.0f;

    for (int p = pairblk; p < P; p += PSTRIDE) {
        #pragma unroll
        for (int side = 0; side < 2; ++side) {
            const int gg = side ? (G - 1 - p) : p;
            const int i0 = gg << 3;
            float tg[ROWS], pg[ROWS];
            #pragma unroll
            for (int k = 0; k < ROWS; ++k) { tg[k] = targets[i0 + k]; pg[k] = preds[i0 + k]; }

            // intra-group 8x8 strict upper triangle (28 pairs), exact tie semantics
            if (sub == side && tid < 64) {
                int ii = tid >> 3, jj = tid & 7;
                if (ii < jj) {
                    float td = tg[ii] - tg[jj], pd = pg[ii] - pg[jj];
                    float cs = (td > 0.0f) ? 1.0f : ((td < 0.0f) ? -1.0f : 0.0f);
                    extra += fmaxf(fmaf(-cs, pd, margin), 0.0f);
                }
            }

            const int lo = i0 + ROWS;          // multiple of 8 -> float4 aligned
            const int len = N - lo;
            const int len4 = len >> 2;
            const float4* tj4 = (const float4*)(targets + lo);
            const float4* pj4 = (const float4*)(preds + lo);
            for (int idx = sub * NT + tid; idx < len4; idx += NT * SPLIT) {
                float4 tv = tj4[idx];
                float4 pv = pj4[idx];
                do_j(tv.x, pv.x, tg, pg, margin, av);
                do_j(tv.y, pv.y, tg, pg, margin, av);
                do_j(tv.z, pv.z, tg, pg, margin, av);
                do_j(tv.w, pv.w, tg, pg, margin, av);
            }
            for (int j = lo + (len4 << 2) + sub * NT + tid; j < N; j += NT * SPLIT) {
                do_j(targets[j], preds[j], tg, pg, margin, av);   // dead when N % 4 == 0
            }
        }
    }

    // ---- leftovers for general N (dead when N % 16 == 0) ----
    if (pairblk == 0) {
        if (G & 1) {
            const int i0 = (G >> 1) << 3;
            for (int k = 0; k < ROWS && i0 + k < N; ++k) {
                const int i = i0 + k;
                for (int j = i + 1 + sub * NT + tid; j < N; j += NT * SPLIT) {
                    float td = targets[i] - targets[j], pd = preds[i] - preds[j];
                    float cs = (td > 0.0f) ? 1.0f : ((td < 0.0f) ? -1.0f : 0.0f);
                    extra += fmaxf(fmaf(-cs, pd, margin), 0.0f);
                }
            }
        }
        for (int i = G << 3; i < N; ++i) {
            for (int j = i + 1 + sub * NT + tid; j < N; j += NT * SPLIT) {
                float td = targets[i] - targets[j], pd = preds[i] - preds[j];
                float cs = (td > 0.0f) ? 1.0f : ((td < 0.0f) ? -1.0f : 0.0f);
                extra += fmaxf(fmaf(-cs, pd, margin), 0.0f);
            }
        }
    }

    // ---- block reduce (f64), plain store; next dispatch reads it (safe) ----
    double tot = (double)extra;
    #pragma unroll
    for (int k = 0; k < ROWS; ++k) tot += (double)av[k];
    #pragma unroll
    for (int off = 32; off; off >>= 1) tot += __shfl_down(tot, off, 64);
    __syncthreads();                       // sred reads done before redd overlay writes
    if (lane == 0) redd[wave] = tot;
    __syncthreads();
    if (tid == 0) {
        double bt = 0.0;
        for (int w = 0; w < NW; ++w) bt += redd[w];
        partials[blockIdx.x] = bt;
    }
}

// ---- kernel 2: sum partials -> out ----
__global__ __launch_bounds__(256)
void finalize_kernel(const double* __restrict__ partials, int nparts,
                     float* __restrict__ out, double inv_pairs)
{
    __shared__ double red[4];
    const int tid = threadIdx.x, lane = tid & 63, wave = tid >> 6;
    double s = 0.0;
    for (int i = tid; i < nparts; i += 256) s += partials[i];
    #pragma unroll
    for (int off = 32; off; off >>= 1) s += __shfl_down(s, off, 64);
    if (lane == 0) red[wave] = s;
    __syncthreads();
    if (tid == 0) {
        double t = 0.0;
        for (int w = 0; w < 4; ++w) t += red[w];
        out[0] = (float)(t * inv_pairs);
    }
}

extern "C" void kernel_launch(void* const* d_in, const int* in_sizes, int n_in,
                              void* d_out, int out_size, void* d_ws, size_t ws_size,
                              hipStream_t stream) {
    const float* preds   = (const float*)d_in[0];
    const float* targets = (const float*)d_in[1];
    float* out = (float*)d_out;
    int N = in_sizes[0];

    double* partials = (double*)d_ws;                       // up to 1024 * 8 B

    const int G = N >> 3;
    const int P = G >> 1;
    int NB = (P > 0 ? P : 1) * SPLIT;                       // N=8192 -> 512*2 = 1024 blocks
    if (NB > 1024) NB = 1024;

    const double inv_pairs = 2.0 / ((double)N * (double)(N - 1));
    pair_kernel<<<NB, NT, 0, stream>>>(preds, targets, partials, N);
    finalize_kernel<<<1, 256, 0, stream>>>(partials, NB, out, inv_pairs);
}

// Round 11
// 17.648 us; speedup vs baseline: 1.0602x; 1.0602x over previous
//
#include <hip/hip_runtime.h>

#define NT    512   // threads per pair-kernel block (8 waves)
#define NB    512   // blocks: 2 per CU; each handles 2 group-pairs
#define SPLIT 2     // sub-blocks per row-group pair
#define ROWS  8     // rows register-blocked per group
#define NW    (NT / 64)

__device__ __forceinline__ float pair_loss(float tt, float pp, float tj, float pj, float margin) {
    float td = tt - tj;
    float pd = pp - pj;
    float cs = copysignf(1.0f, td);            // ties -> +/-1; off-diagonal ties have ~0 probability
    return fmaxf(fmaf(-cs, pd, margin), 0.0f);
}

__device__ __forceinline__ void do_j(float tj, float pj, const float* tg, const float* pg,
                                     float margin, float* av) {
    #pragma unroll
    for (int k = 0; k < ROWS; ++k) av[k] += pair_loss(tg[k], pg[k], tj, pj, margin);
}

// ---- kernel 1: all pairs; lean f32 margin prologue; plain partial stores ----
__global__ __launch_bounds__(NT, 4)
void pair_kernel(const float* __restrict__ preds, const float* __restrict__ targets,
                 double* __restrict__ partials, int N)
{
    const int tid = threadIdx.x, lane = tid & 63, wave = tid >> 6;
    __shared__ float  sred[2 * NW];
    __shared__ double redd[NW];

    // ---- lean f32 margin = 0.25 * std(targets, ddof=1), redundant per block ----
    float margin;
    {
        float s = 0.0f, s2 = 0.0f;
        const int n4 = N >> 2;
        const float4* t4 = (const float4*)targets;
        #pragma unroll 4
        for (int i = tid; i < n4; i += NT) {
            float4 v = t4[i];
            s  += v.x + v.y + v.z + v.w;
            s2 += v.x * v.x + v.y * v.y + v.z * v.z + v.w * v.w;
        }
        for (int i = (n4 << 2) + tid; i < N; i += NT) { float t = targets[i]; s += t; s2 += t * t; }
        #pragma unroll
        for (int off = 32; off; off >>= 1) { s += __shfl_xor(s, off, 64); s2 += __shfl_xor(s2, off, 64); }
        if (lane == 0) { sred[wave] = s; sred[NW + wave] = s2; }
        __syncthreads();
        float S = 0.0f, S2 = 0.0f;
        #pragma unroll
        for (int w = 0; w < NW; ++w) { S += sred[w]; S2 += sred[NW + w]; }
        float mean = S / (float)N;
        float var  = (S2 - (float)N * mean * mean) / (float)(N - 1);
        margin = 0.25f * sqrtf(fmaxf(var, 0.0f));
    }

    const int G = N >> 3;                 // groups of ROWS rows
    const int P = G >> 1;                 // group pairs (g, G-1-g): uniform combined work
    const int sub = (int)(blockIdx.x & (SPLIT - 1));
    const int pairblk = (int)(blockIdx.x >> 1);       // / SPLIT
    const int PSTRIDE = NB >> 1;                      // / SPLIT

    float av[ROWS];
    #pragma unroll
    for (int k = 0; k < ROWS; ++k) av[k] = 0.0f;
    float extra = 0.0f;

    for (int p = pairblk; p < P; p += PSTRIDE) {
        // ---- load BOTH sides' row values up-front (block-uniform -> s_loads, latency hidden) ----
        const int gA = p;
        const int gB = G - 1 - p;
        const int iA = gA << 3, iB = gB << 3;
        float tgA[ROWS], pgA[ROWS], tgB[ROWS], pgB[ROWS];
        #pragma unroll
        for (int k = 0; k < ROWS; ++k) {
            tgA[k] = targets[iA + k]; pgA[k] = preds[iA + k];
            tgB[k] = targets[iB + k]; pgB[k] = preds[iB + k];
        }

        // intra-group triangles (exact tie semantics), one wave-worth of lanes each
        if (tid < 64 && sub == 0) {
            int ii = tid >> 3, jj = tid & 7;
            if (ii < jj) {
                float td = tgA[ii] - tgA[jj], pd = pgA[ii] - pgA[jj];
                float cs = (td > 0.0f) ? 1.0f : ((td < 0.0f) ? -1.0f : 0.0f);
                extra += fmaxf(fmaf(-cs, pd, margin), 0.0f);
            }
        }
        if (tid < 64 && sub == 1) {
            int ii = tid >> 3, jj = tid & 7;
            if (ii < jj) {
                float td = tgB[ii] - tgB[jj], pd = pgB[ii] - pgB[jj];
                float cs = (td > 0.0f) ? 1.0f : ((td < 0.0f) ? -1.0f : 0.0f);
                extra += fmaxf(fmaf(-cs, pd, margin), 0.0f);
            }
        }

        #pragma unroll
        for (int side = 0; side < 2; ++side) {
            const int i0 = side ? iB : iA;
            const float* tg = side ? tgB : tgA;
            const float* pg = side ? pgB : pgA;

            const int lo = i0 + ROWS;          // multiple of 8 -> float4 aligned
            const int len = N - lo;
            const int len4 = len >> 2;
            const float4* tj4 = (const float4*)(targets + lo);
            const float4* pj4 = (const float4*)(preds + lo);
            for (int idx = sub * NT + tid; idx < len4; idx += NT * SPLIT) {
                float4 tv = tj4[idx];
                float4 pv = pj4[idx];
                do_j(tv.x, pv.x, tg, pg, margin, av);
                do_j(tv.y, pv.y, tg, pg, margin, av);
                do_j(tv.z, pv.z, tg, pg, margin, av);
                do_j(tv.w, pv.w, tg, pg, margin, av);
            }
            for (int j = lo + (len4 << 2) + sub * NT + tid; j < N; j += NT * SPLIT) {
                do_j(targets[j], preds[j], tg, pg, margin, av);   // dead when N % 4 == 0
            }
        }
    }

    // ---- leftovers for general N (dead when N % 16 == 0) ----
    if (pairblk == 0) {
        if (G & 1) {
            const int i0 = (G >> 1) << 3;
            for (int k = 0; k < ROWS && i0 + k < N; ++k) {
                const int i = i0 + k;
                for (int j = i + 1 + sub * NT + tid; j < N; j += NT * SPLIT) {
                    float td = targets[i] - targets[j], pd = preds[i] - preds[j];
                    float cs = (td > 0.0f) ? 1.0f : ((td < 0.0f) ? -1.0f : 0.0f);
                    extra += fmaxf(fmaf(-cs, pd, margin), 0.0f);
                }
            }
        }
        for (int i = G << 3; i < N; ++i) {
            for (int j = i + 1 + sub * NT + tid; j < N; j += NT * SPLIT) {
                float td = targets[i] - targets[j], pd = preds[i] - preds[j];
                float cs = (td > 0.0f) ? 1.0f : ((td < 0.0f) ? -1.0f : 0.0f);
                extra += fmaxf(fmaf(-cs, pd, margin), 0.0f);
            }
        }
    }

    // ---- block reduce (f64), plain store; next dispatch reads it (safe) ----
    double tot = (double)extra;
    #pragma unroll
    for (int k = 0; k < ROWS; ++k) tot += (double)av[k];
    #pragma unroll
    for (int off = 32; off; off >>= 1) tot += __shfl_down(tot, off, 64);
    __syncthreads();                       // sred reads done before redd overlay writes
    if (lane == 0) redd[wave] = tot;
    __syncthreads();
    if (tid == 0) {
        double bt = 0.0;
        for (int w = 0; w < NW; ++w) bt += redd[w];
        partials[blockIdx.x] = bt;
    }
}

// ---- kernel 2: sum partials -> out ----
__global__ __launch_bounds__(256)
void finalize_kernel(const double* __restrict__ partials, int nparts,
                     float* __restrict__ out, double inv_pairs)
{
    __shared__ double red[4];
    const int tid = threadIdx.x, lane = tid & 63, wave = tid >> 6;
    double s = 0.0;
    for (int i = tid; i < nparts; i += 256) s += partials[i];
    #pragma unroll
    for (int off = 32; off; off >>= 1) s += __shfl_down(s, off, 64);
    if (lane == 0) red[wave] = s;
    __syncthreads();
    if (tid == 0) {
        double t = 0.0;
        for (int w = 0; w < 4; ++w) t += red[w];
        out[0] = (float)(t * inv_pairs);
    }
}

extern "C" void kernel_launch(void* const* d_in, const int* in_sizes, int n_in,
                              void* d_out, int out_size, void* d_ws, size_t ws_size,
                              hipStream_t stream) {
    const float* preds   = (const float*)d_in[0];
    const float* targets = (const float*)d_in[1];
    float* out = (float*)d_out;
    int N = in_sizes[0];

    double* partials = (double*)d_ws;     // NB * 8 B

    const double inv_pairs = 2.0 / ((double)N * (double)(N - 1));
    pair_kernel<<<NB, NT, 0, stream>>>(preds, targets, partials, N);
    finalize_kernel<<<1, 256, 0, stream>>>(partials, NB, out, inv_pairs);
}